// Round 4
// baseline (56.377 us; speedup 1.0000x reference)
//
#include <hip/hip_runtime.h>
#include <math.h>

constexpr int CIN = 32;   // input channels (K)
constexpr int NS  = 32;   // sums (output channels)

typedef __attribute__((ext_vector_type(8)))  short  short8;
typedef __attribute__((ext_vector_type(16))) float  f32x16;

__device__ __forceinline__ short f2bf(float f) {
    union { float f; unsigned u; } v; v.f = f;
    unsigned r = (v.u + 0x7FFFu + ((v.u >> 16) & 1u)) >> 16;   // RNE
    return (short)r;
}

// One wave = 32 pixels via mfma_f32_32x32x16_bf16 (round-2 structure),
// with the w-softmax fused as a per-wave prologue that runs under the
// x-load HBM latency (x loads issued first in source order).
// A frag (w):  lane holds row s=lane&31, k=8*(lane>>5)+j
// B frag (p):  lane holds col pix=lane&31, k=8*(lane>>5)+j
// D:           lane holds col pix, rows s=(reg&3)+8*(reg>>2)+4*(lane>>5)
__global__ __launch_bounds__(256)
void logconv_fused(const float* __restrict__ x,
                   const float* __restrict__ acc,
                   float* __restrict__ out) {
    const int lane = threadIdx.x & 63;
    const int wid  = threadIdx.x >> 6;
    const int r    = lane & 31;          // pixel-in-tile / s-row for A
    const int h    = lane >> 5;          // K-half
    const long pix = (long)blockIdx.x * 128 + wid * 32 + r;

    // ---- x loads first: HBM latency overlaps the w prologue below ----
    const float* xp = x + pix * CIN + 8 * h;
    float4 a0 = *(const float4*)(xp);        // c = 8h .. 8h+3
    float4 a1 = *(const float4*)(xp + 4);    // c = 8h+4 .. 8h+7
    float4 a2 = *(const float4*)(xp + 16);   // c = 16+8h ..
    float4 a3 = *(const float4*)(xp + 20);

    // ---- per-lane A fragment: column s=r of softmax_c(acc[c][s]) ----
    float a[CIN];
#pragma unroll
    for (int c = 0; c < CIN; ++c) a[c] = acc[c * NS + r];   // broadcast-coalesced
    float wm = a[0];
#pragma unroll
    for (int c = 1; c < CIN; ++c) wm = fmaxf(wm, a[c]);
    float wsum = 0.f;
#pragma unroll
    for (int c = 0; c < CIN; ++c) { a[c] = __expf(a[c] - wm); wsum += a[c]; }
    float winv = 1.f / wsum;
    short8 w0, w1;
#pragma unroll
    for (int j = 0; j < 8; ++j) {        // static indices only (rule #20)
        w0[j] = f2bf((h ? a[8 + j]  : a[j])      * winv);
        w1[j] = f2bf((h ? a[24 + j] : a[16 + j]) * winv);
    }

    // ---- main tile compute (identical to round-2 winner) ----
    float xv[16] = {a0.x,a0.y,a0.z,a0.w, a1.x,a1.y,a1.z,a1.w,
                    a2.x,a2.y,a2.z,a2.w, a3.x,a3.y,a3.z,a3.w};

    float pm = xv[0];
#pragma unroll
    for (int j = 1; j < 16; ++j) pm = fmaxf(pm, xv[j]);
    pm = fmaxf(pm, __shfl_xor(pm, 32));      // other 16 channels of same pixel

    short8 p0, p1;
#pragma unroll
    for (int j = 0; j < 8; ++j) p0[j] = f2bf(__expf(xv[j]     - pm));
#pragma unroll
    for (int j = 0; j < 8; ++j) p1[j] = f2bf(__expf(xv[8 + j] - pm));

    f32x16 accv;
#pragma unroll
    for (int i = 0; i < 16; ++i) accv[i] = 0.f;
    accv = __builtin_amdgcn_mfma_f32_32x32x16_bf16(w0, p0, accv, 0, 0, 0);
    accv = __builtin_amdgcn_mfma_f32_32x32x16_bf16(w1, p1, accv, 0, 0, 0);

    // lane owns pixel `pix`; acc[4g+i] is s = 8g + 4h + i  -> float4 stores
    float* op = out + pix * NS;
#pragma unroll
    for (int g = 0; g < 4; ++g) {
        float4 v;
        v.x = pm + __logf(accv[4 * g + 0]);
        v.y = pm + __logf(accv[4 * g + 1]);
        v.z = pm + __logf(accv[4 * g + 2]);
        v.w = pm + __logf(accv[4 * g + 3]);
        *(float4*)(op + 8 * g + 4 * h) = v;
    }
}

extern "C" void kernel_launch(void* const* d_in, const int* in_sizes, int n_in,
                              void* d_out, int out_size, void* d_ws, size_t ws_size,
                              hipStream_t stream) {
    const float* x   = (const float*)d_in[0];   // [32,128,128,32] f32
    const float* acc = (const float*)d_in[1];   // [1,1,32,32] f32
    float* out = (float*)d_out;

    int npix = in_sizes[0] / CIN;               // 524288
    int grid = npix / 128;                      // 4096 blocks x 256 thr (4 waves)
    logconv_fused<<<grid, 256, 0, stream>>>(x, acc, out);
}

// Round 5
// 31.566 us; speedup vs baseline: 1.7860x; 1.7860x over previous
//
#include <hip/hip_runtime.h>
#include <math.h>

constexpr int CIN = 32;   // input channels (K)
constexpr int NS  = 32;   // sums (output channels)

typedef __attribute__((ext_vector_type(8)))  short  short8;
typedef __attribute__((ext_vector_type(16))) float  f32x16;

__device__ __forceinline__ short f2bf(float f) {
    union { float f; unsigned u; } v; v.f = f;
    unsigned r = (v.u + 0x7FFFu + ((v.u >> 16) & 1u)) >> 16;   // RNE
    return (short)r;
}

// w^T in bf16: wT[s][c] = softmax_c(acc[c][s])  (tiny, one dispatch)
__global__ void compute_w_kernel(const float* __restrict__ acc,
                                 short* __restrict__ wT) {
    int s = threadIdx.x;
    if (s >= NS) return;
    float a[CIN];
    float m = -INFINITY;
#pragma unroll
    for (int c = 0; c < CIN; ++c) { a[c] = acc[c * NS + s]; m = fmaxf(m, a[c]); }
    float sum = 0.f;
#pragma unroll
    for (int c = 0; c < CIN; ++c) { a[c] = __expf(a[c] - m); sum += a[c]; }
    float inv = 1.f / sum;
#pragma unroll
    for (int c = 0; c < CIN; ++c) wT[s * CIN + c] = f2bf(a[c] * inv);
}

// Round-2 structure, 2 independent tiles per wave (64 pixels), all loads
// issued up front for 2x memory-level parallelism. No fused prologue.
// A frag (w):  lane holds row s=lane&31, k=8*(lane>>5)+j
// B frag (p):  lane holds col pix=lane&31, k=8*(lane>>5)+j
// D:           lane holds col pix, rows s=(reg&3)+8*(reg>>2)+4*(lane>>5)
__global__ __launch_bounds__(256)
void logconv_mfma(const float* __restrict__ x,
                  const short* __restrict__ wT,
                  float* __restrict__ out) {
    const int lane = threadIdx.x & 63;
    const int wid  = threadIdx.x >> 6;
    const int r    = lane & 31;          // pixel-in-tile / s-row for A
    const int h    = lane >> 5;          // K-half
    const long pixA = (long)blockIdx.x * 256 + wid * 64 + r;
    const long pixB = pixA + 32;

    // w fragments (L1-resident after first wave)
    const short* wp = wT + r * CIN + 8 * h;
    short8 w0 = *(const short8*)(wp);        // k = 8h+j
    short8 w1 = *(const short8*)(wp + 16);   // k = 16+8h+j

    // ---- both tiles' x loads issued before any compute ----
    const float* xpA = x + pixA * CIN + 8 * h;
    float4 a0 = *(const float4*)(xpA);
    float4 a1 = *(const float4*)(xpA + 4);
    float4 a2 = *(const float4*)(xpA + 16);
    float4 a3 = *(const float4*)(xpA + 20);
    const float* xpB = x + pixB * CIN + 8 * h;
    float4 b0 = *(const float4*)(xpB);
    float4 b1 = *(const float4*)(xpB + 4);
    float4 b2 = *(const float4*)(xpB + 16);
    float4 b3 = *(const float4*)(xpB + 20);

#define COMPUTE(PIX, R0, R1, R2, R3) do {                               \
        float xv[16] = {R0.x,R0.y,R0.z,R0.w, R1.x,R1.y,R1.z,R1.w,       \
                        R2.x,R2.y,R2.z,R2.w, R3.x,R3.y,R3.z,R3.w};      \
        float pm = xv[0];                                               \
        _Pragma("unroll")                                               \
        for (int j = 1; j < 16; ++j) pm = fmaxf(pm, xv[j]);             \
        pm = fmaxf(pm, __shfl_xor(pm, 32));                             \
        short8 p0, p1;                                                  \
        _Pragma("unroll")                                               \
        for (int j = 0; j < 8; ++j) p0[j] = f2bf(__expf(xv[j]     - pm)); \
        _Pragma("unroll")                                               \
        for (int j = 0; j < 8; ++j) p1[j] = f2bf(__expf(xv[8 + j] - pm)); \
        f32x16 accv;                                                    \
        _Pragma("unroll")                                               \
        for (int i = 0; i < 16; ++i) accv[i] = 0.f;                     \
        accv = __builtin_amdgcn_mfma_f32_32x32x16_bf16(w0, p0, accv, 0, 0, 0); \
        accv = __builtin_amdgcn_mfma_f32_32x32x16_bf16(w1, p1, accv, 0, 0, 0); \
        float* op_ = out + (PIX) * NS;                                  \
        _Pragma("unroll")                                               \
        for (int g = 0; g < 4; ++g) {                                   \
            float4 v;                                                   \
            v.x = pm + __logf(accv[4 * g + 0]);                         \
            v.y = pm + __logf(accv[4 * g + 1]);                         \
            v.z = pm + __logf(accv[4 * g + 2]);                         \
            v.w = pm + __logf(accv[4 * g + 3]);                         \
            *(float4*)(op_ + 8 * g + 4 * h) = v;                        \
        }                                                               \
    } while (0)

    COMPUTE(pixA, a0, a1, a2, a3);
    COMPUTE(pixB, b0, b1, b2, b3);
#undef COMPUTE
}

extern "C" void kernel_launch(void* const* d_in, const int* in_sizes, int n_in,
                              void* d_out, int out_size, void* d_ws, size_t ws_size,
                              hipStream_t stream) {
    const float* x   = (const float*)d_in[0];   // [32,128,128,32] f32
    const float* acc = (const float*)d_in[1];   // [1,1,32,32] f32
    float* out = (float*)d_out;
    short* wT  = (short*)d_ws;                  // 32*32 bf16 (transposed)

    compute_w_kernel<<<1, 64, 0, stream>>>(acc, wT);

    int npix = in_sizes[0] / CIN;               // 524288
    int grid = npix / 256;                      // 2048 blocks x 256 thr (4 waves x 2 tiles)
    logconv_mfma<<<grid, 256, 0, stream>>>(x, wT, out);
}

// Round 6
// 28.311 us; speedup vs baseline: 1.9913x; 1.1150x over previous
//
#include <hip/hip_runtime.h>
#include <math.h>

constexpr int CIN = 32;   // input channels (K)
constexpr int NS  = 32;   // sums (output channels)

typedef __attribute__((ext_vector_type(8)))  short  short8;
typedef __attribute__((ext_vector_type(16))) float  f32x16;

__device__ __forceinline__ short f2bf(float f) {
    union { float f; unsigned u; } v; v.f = f;
    unsigned r = (v.u + 0x7FFFu + ((v.u >> 16) & 1u)) >> 16;   // RNE
    return (short)r;
}

// Single fused kernel. Per block: threads 0-31 compute the w-softmax ONCE
// into per-lane pre-formatted A-fragments in LDS (2 KB); all waves issue
// their x loads BEFORE the barrier so the prologue hides under HBM latency.
// Then the R5-verified 2-tile MFMA body.
// A frag (w):  lane holds row s=lane&31, k=8*(lane>>5)+j
// B frag (p):  lane holds col pix=lane&31, k=8*(lane>>5)+j
// D:           lane holds col pix, rows s=(reg&3)+8*(reg>>2)+4*(lane>>5)
__global__ __launch_bounds__(256)
void logconv_fused(const float* __restrict__ x,
                   const float* __restrict__ acc,
                   float* __restrict__ out) {
    __shared__ short8 wfrag[64][2];   // [lane][frag] : 2 KB

    const int lane = threadIdx.x & 63;
    const int wid  = threadIdx.x >> 6;
    const int r    = lane & 31;          // pixel-in-tile / s-row for A
    const int h    = lane >> 5;          // K-half
    const long pixA = (long)blockIdx.x * 256 + wid * 64 + r;
    const long pixB = pixA + 32;

    // ---- both tiles' x loads issued before the barrier (MLP, hides prologue) ----
    const float* xpA = x + pixA * CIN + 8 * h;
    float4 a0 = *(const float4*)(xpA);
    float4 a1 = *(const float4*)(xpA + 4);
    float4 a2 = *(const float4*)(xpA + 16);
    float4 a3 = *(const float4*)(xpA + 20);
    const float* xpB = x + pixB * CIN + 8 * h;
    float4 b0 = *(const float4*)(xpB);
    float4 b1 = *(const float4*)(xpB + 4);
    float4 b2 = *(const float4*)(xpB + 16);
    float4 b3 = *(const float4*)(xpB + 20);

    // ---- per-block w-softmax prologue (threads 0-31 only) ----
    if (threadIdx.x < 32) {
        const int s = threadIdx.x;       // output-channel column
        float a[CIN];
#pragma unroll
        for (int c = 0; c < CIN; ++c) a[c] = acc[c * NS + s];
        float wm = a[0];
#pragma unroll
        for (int c = 1; c < CIN; ++c) wm = fmaxf(wm, a[c]);
        float wsum = 0.f;
#pragma unroll
        for (int c = 0; c < CIN; ++c) { a[c] = __expf(a[c] - wm); wsum += a[c]; }
        float winv = 1.f / wsum;
        short8 f00, f01, f10, f11;       // [h][frag] for this s-row
#pragma unroll
        for (int j = 0; j < 8; ++j) {
            f00[j] = f2bf(a[j]      * winv);   // h=0, k=j
            f10[j] = f2bf(a[8 + j]  * winv);   // h=1, k=j
            f01[j] = f2bf(a[16 + j] * winv);   // h=0, k'=j
            f11[j] = f2bf(a[24 + j] * winv);   // h=1, k'=j
        }
        wfrag[s][0]      = f00;
        wfrag[s][1]      = f01;
        wfrag[32 + s][0] = f10;
        wfrag[32 + s][1] = f11;
    }
    __syncthreads();

    const short8 w0 = wfrag[lane][0];    // lane*32 B: 4-lane groups span all banks
    const short8 w1 = wfrag[lane][1];

#define COMPUTE(PIX, R0, R1, R2, R3) do {                               \
        float xv[16] = {R0.x,R0.y,R0.z,R0.w, R1.x,R1.y,R1.z,R1.w,       \
                        R2.x,R2.y,R2.z,R2.w, R3.x,R3.y,R3.z,R3.w};      \
        float pm = xv[0];                                               \
        _Pragma("unroll")                                               \
        for (int j = 1; j < 16; ++j) pm = fmaxf(pm, xv[j]);             \
        pm = fmaxf(pm, __shfl_xor(pm, 32));                             \
        short8 p0, p1;                                                  \
        _Pragma("unroll")                                               \
        for (int j = 0; j < 8; ++j) p0[j] = f2bf(__expf(xv[j]     - pm)); \
        _Pragma("unroll")                                               \
        for (int j = 0; j < 8; ++j) p1[j] = f2bf(__expf(xv[8 + j] - pm)); \
        f32x16 accv;                                                    \
        _Pragma("unroll")                                               \
        for (int i = 0; i < 16; ++i) accv[i] = 0.f;                     \
        accv = __builtin_amdgcn_mfma_f32_32x32x16_bf16(w0, p0, accv, 0, 0, 0); \
        accv = __builtin_amdgcn_mfma_f32_32x32x16_bf16(w1, p1, accv, 0, 0, 0); \
        float* op_ = out + (PIX) * NS;                                  \
        _Pragma("unroll")                                               \
        for (int g = 0; g < 4; ++g) {                                   \
            float4 v;                                                   \
            v.x = pm + __logf(accv[4 * g + 0]);                         \
            v.y = pm + __logf(accv[4 * g + 1]);                         \
            v.z = pm + __logf(accv[4 * g + 2]);                         \
            v.w = pm + __logf(accv[4 * g + 3]);                         \
            *(float4*)(op_ + 8 * g + 4 * h) = v;                        \
        }                                                               \
    } while (0)

    COMPUTE(pixA, a0, a1, a2, a3);
    COMPUTE(pixB, b0, b1, b2, b3);
#undef COMPUTE
}

extern "C" void kernel_launch(void* const* d_in, const int* in_sizes, int n_in,
                              void* d_out, int out_size, void* d_ws, size_t ws_size,
                              hipStream_t stream) {
    const float* x   = (const float*)d_in[0];   // [32,128,128,32] f32
    const float* acc = (const float*)d_in[1];   // [1,1,32,32] f32
    float* out = (float*)d_out;

    int npix = in_sizes[0] / CIN;               // 524288
    int grid = npix / 256;                      // 2048 blocks x 256 thr (4 waves x 2 tiles)
    logconv_fused<<<grid, 256, 0, stream>>>(x, acc, out);
}